// Round 9
// baseline (181.899 us; speedup 1.0000x reference)
//
#include <hip/hip_runtime.h>

typedef unsigned short u16;
typedef u16 u16x4 __attribute__((ext_vector_type(4)));
typedef u16 u16x8 __attribute__((ext_vector_type(8)));
typedef __bf16 bf16x8 __attribute__((ext_vector_type(8)));
typedef float floatx4 __attribute__((ext_vector_type(4)));

#define N_EMBD 1024
#define N_HEAD 16
#define HEAD_DIM 64
#define SEQ 2048
#define BATCH 2
#define M_ROWS (BATCH * SEQ)  // 4096

typedef __attribute__((address_space(1))) const unsigned char ga_t;
typedef __attribute__((address_space(3))) unsigned char la_t;

#if __has_builtin(__builtin_amdgcn_exp2f)
#define EXP2(x) __builtin_amdgcn_exp2f(x)
#else
#define EXP2(x) exp2f(x)
#endif

// native gfx950 f32->bf16 (RNE), 1 instr
__device__ __forceinline__ u16 cvt_bf16(float f) {
  return __builtin_bit_cast(u16, (__bf16)f);
}

// ======== prep: convert x (blocks 0..2047) + transpose both weights ========
__global__ __launch_bounds__(256) void prep(const float* __restrict__ x,
                                            u16* __restrict__ xb,
                                            const float* __restrict__ wa,
                                            const float* __restrict__ wp,
                                            u16* __restrict__ outa,
                                            u16* __restrict__ outp) {
  const int bid = blockIdx.x;
  if (bid < 2048) {  // convert_x
    const long i = ((long)bid * 256 + threadIdx.x) * 8;
    const float4 f0 = *(const float4*)&x[i];
    const float4 f1 = *(const float4*)&x[i + 4];
    u16x8 p;
    p[0] = cvt_bf16(f0.x); p[1] = cvt_bf16(f0.y);
    p[2] = cvt_bf16(f0.z); p[3] = cvt_bf16(f0.w);
    p[4] = cvt_bf16(f1.x); p[5] = cvt_bf16(f1.y);
    p[6] = cvt_bf16(f1.z); p[7] = cvt_bf16(f1.w);
    *(u16x8*)&xb[i] = p;
    return;
  }
  // transpose: linearized (gx 0..127, gy 0..31); gx<96: w_attn, else w_proj
  __shared__ u16 tile[32][33];
  const int t = bid - 2048;
  const int gx = t & 127;
  const int gy = t >> 7;
  const int R = N_EMBD;
  const float* in;
  u16* out;
  int C, bx;
  if (gx < 96) {
    in = wa; out = outa; C = 3 * N_EMBD; bx = gx * 32;
  } else {
    in = wp; out = outp; C = N_EMBD; bx = (gx - 96) * 32;
  }
  const int by = gy * 32;
  const int tx = threadIdx.x & 31;
  const int ty = threadIdx.x >> 5;
#pragma unroll
  for (int j = 0; j < 32; j += 8)
    tile[ty + j][tx] = cvt_bf16(in[(long)(by + ty + j) * C + bx + tx]);
  __syncthreads();
#pragma unroll
  for (int j = 0; j < 32; j += 8)
    out[(long)(bx + ty + j) * R + by + tx] = tile[tx][ty + j];
}

// ======== gemm256 — qkv GEMM: 256x256 tile, BK=64, 8 waves, reg-pipelined ==
// Grid 12x16 = 192 blocks (%8==0), 512 threads, LDS 128KB dynamic (2 bufs).
// Per K-tile: ds_read ALL 24 frags -> lgkmcnt(0)+barrier1 (buffer free) ->
// stage(kt+2) into freed buffer + vmcnt(8) (own kt+1 loads landed; kt+2 in
// flight ACROSS barrier) -> barrier2 (kt+1 visible block-wide) -> 64 MFMA
// from registers. Loads get a full K-tile of compute to land; MFMA never
// waits on LDS. Swizzle: 8 slots, slot^(row&7) both sides (rule #21),
// hand-checked <=2-way on all reads.
#define GBK 64

__device__ __forceinline__ void stage256(const u16* __restrict__ A,
                                         const u16* __restrict__ Bt, int bm,
                                         int bn, int kt, int tid, u16* as,
                                         u16* bs) {
#pragma unroll
  for (int i = 0; i < 4; ++i) {
    const int p = tid + 512 * i;
    const int row = p >> 3;              // 0..255
    const int sl = (p & 7) ^ (row & 7);  // inverse-swizzled 16B source slot
    const int wb = (i * 512 + (tid & 448)) * 8;  // wave-uniform dest (u16)
    __builtin_amdgcn_global_load_lds(
        (ga_t*)&A[(long)(bm + row) * N_EMBD + kt + sl * 8], (la_t*)&as[wb], 16,
        0, 0);
    __builtin_amdgcn_global_load_lds(
        (ga_t*)&Bt[(long)(bn + row) * N_EMBD + kt + sl * 8], (la_t*)&bs[wb], 16,
        0, 0);
  }
}

__global__ __launch_bounds__(512) void gemm256(
    const u16* __restrict__ A, const u16* __restrict__ Bt,
    const float* __restrict__ bias, u16* __restrict__ qo, u16* __restrict__ ko,
    u16* __restrict__ vo) {
  extern __shared__ u16 smem[];
  u16* As = smem;                 // [2][256*64]
  u16* Bs = smem + 2 * 256 * 64;  // [2][256*64]
  const int tid = threadIdx.x;

  // bijective XCD swizzle (nwg = 192)
  const int nx = gridDim.x;  // 12
  const int nwg = nx * gridDim.y;
  int lin = blockIdx.y * nx + blockIdx.x;
  lin = (lin & 7) * (nwg >> 3) + (lin >> 3);
  const int bm = (lin / nx) * 256;
  const int bn = (lin % nx) * 256;

  const int w = tid >> 6;         // 0..7
  const int l = tid & 63;
  const int wm = (w >> 2) * 128;  // 2 M-rows of waves
  const int wn = (w & 3) * 64;    // 4 N-cols of waves
  const int m16 = l & 15;
  const int quad = l >> 4;
  const int rsw = m16 & 7;  // read-side XOR (row&7 == m16&7 for frag rows)

  floatx4 acc[8][4];
#pragma unroll
  for (int i = 0; i < 8; ++i)
#pragma unroll
    for (int j = 0; j < 4; ++j) acc[i][j] = (floatx4){0.f, 0.f, 0.f, 0.f};

  // prologue: tiles 0,1 in flight; wait tile 0 (8 of tile 1 remain in flight)
  stage256(A, Bt, bm, bn, 0, tid, As, Bs);
  stage256(A, Bt, bm, bn, GBK, tid, As + 256 * 64, Bs + 256 * 64);
  asm volatile("s_waitcnt vmcnt(8)" ::: "memory");
  __builtin_amdgcn_s_barrier();

  for (int kt = 0; kt < 16; ++kt) {
    u16* as = As + (kt & 1) * (256 * 64);
    u16* bs = Bs + (kt & 1) * (256 * 64);

    // all fragments of tile kt -> registers
    bf16x8 af[8][2], bf[4][2];
#pragma unroll
    for (int i = 0; i < 8; ++i)
#pragma unroll
      for (int kk = 0; kk < 2; ++kk)
        af[i][kk] = __builtin_bit_cast(
            bf16x8, *(const u16x8*)&as[(wm + i * 16 + m16) * 64 +
                                       (((kk * 4 + quad) ^ rsw) * 8)]);
#pragma unroll
    for (int j = 0; j < 4; ++j)
#pragma unroll
      for (int kk = 0; kk < 2; ++kk)
        bf[j][kk] = __builtin_bit_cast(
            bf16x8, *(const u16x8*)&bs[(wn + j * 16 + m16) * 64 +
                                       (((kk * 4 + quad) ^ rsw) * 8)]);
    asm volatile("s_waitcnt lgkmcnt(0)" ::: "memory");
    __builtin_amdgcn_s_barrier();  // all waves done READING this buffer

    if (kt + 2 < 16) {
      stage256(A, Bt, bm, bn, (kt + 2) * GBK, tid, as, bs);  // freed buffer
      asm volatile("s_waitcnt vmcnt(8)" ::: "memory");  // own kt+1 loads done
    } else {
      asm volatile("s_waitcnt vmcnt(0)" ::: "memory");
    }
    __builtin_amdgcn_s_barrier();  // tile kt+1 visible to every wave

    __builtin_amdgcn_s_setprio(1);
#pragma unroll
    for (int kk = 0; kk < 2; ++kk)  // kk outermost: no dependent MFMA pairs
#pragma unroll
      for (int i = 0; i < 8; ++i)
#pragma unroll
        for (int j = 0; j < 4; ++j)
          acc[i][j] = __builtin_amdgcn_mfma_f32_16x16x32_bf16(
              af[i][kk], bf[j][kk], acc[i][j], 0, 0, 0);
    __builtin_amdgcn_s_setprio(0);
  }

  // epilogue: scatter q/k (bf16 [B,H,T,D]) and vT ([B,H,D,T])
#pragma unroll
  for (int i = 0; i < 8; ++i) {
#pragma unroll
    for (int j = 0; j < 4; ++j) {
      const int col = bn + wn + j * 16 + m16;
      const float bv = bias[col];
      const int which = col >> 10;  // 0=q 1=k 2=v (wave-uniform per j)
      const int cc = col & 1023;
      const int h = cc >> 6;
      const int dd = cc & 63;
      const int row0 = bm + wm + i * 16 + quad * 4;
      const int b = row0 >> 11;
      const int t0 = row0 & 2047;
      if (which == 2) {
        u16x4 pk;
#pragma unroll
        for (int r = 0; r < 4; ++r) pk[r] = cvt_bf16(acc[i][j][r] + bv);
        *(u16x4*)&vo[(((long)(b * N_HEAD + h)) * HEAD_DIM + dd) * SEQ + t0] =
            pk;
      } else {
        u16* dst = (which == 0) ? qo : ko;
#pragma unroll
        for (int r = 0; r < 4; ++r)
          dst[(((long)(b * N_HEAD + h)) * SEQ + t0 + r) * HEAD_DIM + dd] =
              cvt_bf16(acc[i][j][r] + bv);
      }
    }
  }
}

// ======== gemm128 MODE 1 — proj GEMM (unchanged round-8 triple-buffer) =====
#define BK 32

template <int MODE>
__device__ __forceinline__ void stage128(const u16* __restrict__ A,
                                         const u16* __restrict__ Bt, int bm,
                                         int bn, int kt, int K, int tid,
                                         u16* as, u16* bs) {
  const int w = tid >> 6;
  const int l = tid & 63;
  const int lrow = l >> 2;  // 0..15
#pragma unroll
  for (int p = 0; p < 2; ++p) {  // A: 128 rows
    const int arow = p * 64 + w * 16;
    const int row = arow + lrow;
    const int sl = (l & 3) ^ ((row >> 1) & 3);
    long gA;
    if (MODE == 0) {
      gA = (long)(bm + row) * K + kt + sl * 8;
    } else {
      const int m = bm + row;
      const int b = m >> 11, t = m & 2047;
      const int k0 = kt + sl * 8;
      const int head = k0 >> 6, dd = k0 & 63;
      gA = (((long)(b * N_HEAD + head)) * SEQ + t) * HEAD_DIM + dd;
    }
    __builtin_amdgcn_global_load_lds((ga_t*)(A + gA), (la_t*)&as[arow * BK],
                                     16, 0, 0);
  }
  constexpr int TN = (MODE == 1) ? 64 : 128;
#pragma unroll
  for (int p = 0; p < TN / 64; ++p) {  // B: TN rows
    const int arow = p * 64 + w * 16;
    const int row = arow + lrow;
    const int sl = (l & 3) ^ ((row >> 1) & 3);
    const long gB = (long)(bn + row) * K + kt + sl * 8;
    __builtin_amdgcn_global_load_lds((ga_t*)(Bt + gB), (la_t*)&bs[arow * BK],
                                     16, 0, 0);
  }
}

template <int MODE>
__global__ __launch_bounds__(256) void gemm128(
    const u16* __restrict__ A, const u16* __restrict__ Bt,
    const float* __restrict__ bias, float* __restrict__ out,
    u16* __restrict__ qo, u16* __restrict__ ko, u16* __restrict__ vo, int N,
    int K) {
  constexpr int TN = (MODE == 1) ? 64 : 128;
  constexpr int NJ = TN / 32;
  __shared__ u16 As[3][128 * BK];
  __shared__ u16 Bs[3][TN * BK];
  const int tid = threadIdx.x;

  const int nx = gridDim.x;
  const int nwg = nx * gridDim.y;
  int lin = blockIdx.y * nx + blockIdx.x;
  lin = (lin & 7) * (nwg >> 3) + (lin >> 3);
  const int bm = (lin / nx) * 128;
  const int bn = (lin % nx) * TN;

  const int w = tid >> 6;
  const int l = tid & 63;
  const int wm = (w >> 1) * 64;
  const int wn = (w & 1) * (TN / 2);
  const int m16 = l & 15;
  const int quad = l >> 4;
  const int ksw = (quad ^ ((m16 >> 1) & 3)) * 8;

  floatx4 acc[4][NJ];
#pragma unroll
  for (int i = 0; i < 4; ++i)
#pragma unroll
    for (int j = 0; j < NJ; ++j) acc[i][j] = (floatx4){0.f, 0.f, 0.f, 0.f};

  const int nk = K / BK;
  stage128<MODE>(A, Bt, bm, bn, 0, K, tid, As[0], Bs[0]);
  stage128<MODE>(A, Bt, bm, bn, BK, K, tid, As[1], Bs[1]);

  u16 *a0 = As[0], *a1 = As[1], *a2 = As[2];
  u16 *b0 = Bs[0], *b1 = Bs[1], *b2 = Bs[2];

  for (int t = 0; t < nk; ++t) {
    if (t + 1 < nk) {
      if constexpr (MODE == 0)
        asm volatile("s_waitcnt vmcnt(4)" ::: "memory");
      else
        asm volatile("s_waitcnt vmcnt(3)" ::: "memory");
    } else {
      asm volatile("s_waitcnt vmcnt(0)" ::: "memory");
    }
    __builtin_amdgcn_s_barrier();

    if (t + 2 < nk)
      stage128<MODE>(A, Bt, bm, bn, (t + 2) * BK, K, tid, a2, b2);

    bf16x8 af[4], bfr[NJ];
#pragma unroll
    for (int i = 0; i < 4; ++i)
      af[i] = __builtin_bit_cast(
          bf16x8, *(const u16x8*)&a0[(wm + i * 16 + m16) * BK + ksw]);
#pragma unroll
    for (int j = 0; j < NJ; ++j)
      bfr[j] = __builtin_bit_cast(
          bf16x8, *(const u16x8*)&b0[(wn + j * 16 + m16) * BK + ksw]);
#pragma unroll
    for (int i = 0; i < 4; ++i)
#pragma unroll
      for (int j = 0; j < NJ; ++j)
        acc[i][j] = __builtin_amdgcn_mfma_f32_16x16x32_bf16(af[i], bfr[j],
                                                            acc[i][j], 0, 0, 0);
    u16* ta = a0; a0 = a1; a1 = a2; a2 = ta;
    u16* tb = b0; b0 = b1; b1 = b2; b2 = tb;
  }

#pragma unroll
  for (int i = 0; i < 4; ++i) {
#pragma unroll
    for (int j = 0; j < NJ; ++j) {
      const int col = bn + wn + j * 16 + m16;
      const float bv = bias[col];
      if (MODE == 1) {
#pragma unroll
        for (int r = 0; r < 4; ++r) {
          const int row = bm + wm + i * 16 + quad * 4 + r;
          out[(long)row * N_EMBD + col] = acc[i][j][r] + bv;
        }
      } else {
        const int which = col >> 10;
        const int cc = col & 1023;
        const int h = cc >> 6;
        const int dd = cc & 63;
        const int row0 = bm + wm + i * 16 + quad * 4;
        const int b = row0 >> 11;
        const int t0 = row0 & 2047;
        if (which == 2) {
          u16x4 pk;
#pragma unroll
          for (int r = 0; r < 4; ++r) pk[r] = cvt_bf16(acc[i][j][r] + bv);
          *(u16x4*)&vo[(((long)(b * N_HEAD + h)) * HEAD_DIM + dd) * SEQ + t0] =
              pk;
        } else {
          u16* dst = (which == 0) ? qo : ko;
#pragma unroll
          for (int r = 0; r < 4; ++r)
            dst[(((long)(b * N_HEAD + h)) * SEQ + t0 + r) * HEAD_DIM + dd] =
                cvt_bf16(acc[i][j][r] + bv);
        }
      }
    }
  }
}

// ======== flash attention — uniform blocks: q-tile pair + KV-half split ====
// (unchanged from round 8)
#define BQ 64
#define BKV 64
#define LOG2E 1.44269504f
#define NQT (SEQ / BQ)      // 32 q-tiles
#define NROWS (32 * SEQ)    // 65536 (bh, q) rows

__device__ __forceinline__ void stage_kv(const u16* __restrict__ K,
                                         const u16* __restrict__ Vt, long bh,
                                         int kt, int tid, u16* kl, u16* vl) {
#pragma unroll
  for (int i = 0; i < 2; ++i) {
    const int p = tid + 256 * i;
    const int row = p >> 3;                    // K: key   V: d
    const int slot = (p & 7) ^ (row & 7);      // swizzled 16B source slot
    const int wb = (i * 256 + (tid & 192)) * 8;  // wave-uniform dest (u16)
    __builtin_amdgcn_global_load_lds(
        (ga_t*)&K[(bh * SEQ + kt + row) * HEAD_DIM + slot * 8], (la_t*)&kl[wb],
        16, 0, 0);
    __builtin_amdgcn_global_load_lds(
        (ga_t*)&Vt[(bh * HEAD_DIM + row) * SEQ + kt + slot * 8], (la_t*)&vl[wb],
        16, 0, 0);
  }
}

__global__ __launch_bounds__(256, 4) void flash_attn(
    const u16* __restrict__ Qy, const u16* __restrict__ K,
    const u16* __restrict__ Vt, float* __restrict__ Opart,
    float2* __restrict__ mlpart) {
  const int id = blockIdx.x;
  const int a = id >> 6;        // 0..15: pair index
  const int h = (id >> 5) & 1;  // kv-half
  const long bh = id & 31;      // id%8 = bh%8 -> XCD affinity
  const int tid = threadIdx.x;
  const int w = tid >> 6;
  const int l = tid & 63;
  const int m16 = l & 15;
  const int quad = l >> 4;

  __shared__ u16 Kl[2][BKV * 64];
  __shared__ u16 Vl[2][64 * BKV];
  __shared__ u16 Pl[4][16 * 64];

  const float SC = 0.125f * LOG2E;
  const int sw = (m16 & 7) << 3;

  for (int ph = 0; ph < 2; ++ph) {
    const int iq = ph ? (31 - a) : a;
    const int na = iq + 1;
    const int mid = (na + 1) >> 1;
    const int s0 = h ? mid : 0;
    const int e0 = h ? na : mid;
    const int qglob = iq * BQ + w * 16 + m16;

    bf16x8 qf[2];
    {
      const u16* qrow = Qy + (bh * SEQ + qglob) * HEAD_DIM;
      qf[0] = __builtin_bit_cast(bf16x8, *(const u16x8*)&qrow[quad * 8]);
      qf[1] = __builtin_bit_cast(bf16x8, *(const u16x8*)&qrow[32 + quad * 8]);
    }

    floatx4 Oacc[4];
#pragma unroll
    for (int t = 0; t < 4; ++t) Oacc[t] = (floatx4){0.f, 0.f, 0.f, 0.f};
    float mrow = -1e30f, lsum = 0.f;

    if (s0 < e0) {
      stage_kv(K, Vt, bh, s0 * BKV, tid, Kl[0], Vl[0]);
      __syncthreads();

      for (int it = s0; it < e0; ++it) {
        const int buf = (it - s0) & 1;
        const int kt = it * BKV;
        if (it + 1 < e0)
          stage_kv(K, Vt, bh, kt + BKV, tid, Kl[buf ^ 1], Vl[buf ^ 1]);

        floatx4 s[4];
#pragma unroll
        for (int j = 0; j < 4; ++j) s[j] = (floatx4){0.f, 0.f, 0.f, 0.f};
        __builtin_amdgcn_s_setprio(1);
#pragma unroll
        for (int j = 0; j < 4; ++j)
#pragma unroll
          for (int kk = 0; kk < 2; ++kk) {
            const bf16x8 kf = __builtin_bit_cast(
                bf16x8, *(const u16x8*)&Kl[buf][(j * 16 + m16) * 64 +
                                                ((kk * 32 + quad * 8) ^ sw)]);
            s[j] = __builtin_amdgcn_mfma_f32_16x16x32_bf16(kf, qf[kk], s[j], 0,
                                                           0, 0);
          }
        __builtin_amdgcn_s_setprio(0);
        if (it == na - 1) {
#pragma unroll
          for (int j = 0; j < 4; ++j) {
            const int key0 = kt + j * 16 + quad * 4;
#pragma unroll
            for (int r = 0; r < 4; ++r)
              if (key0 + r > qglob) s[j][r] = -1e30f;
          }
        }

        float tm = s[0][0];
#pragma unroll
        for (int j = 0; j < 4; ++j)
#pragma unroll
          for (int r = 0; r < 4; ++r)
            if (j + r) tm = fmaxf(tm, s[j][r]);
        tm = fmaxf(tm, __shfl_xor(tm, 16, 64));
        tm = fmaxf(tm, __shfl_xor(tm, 32, 64));
        const float pm = tm * SC;
        if (!__all(pm <= mrow + 4.f)) {
          const float mn = fmaxf(mrow, pm);
          const float al = EXP2(mrow - mn);
          mrow = mn;
          lsum *= al;
#pragma unroll
          for (int t = 0; t < 4; ++t)
#pragma unroll
            for (int r = 0; r < 4; ++r) Oacc[t][r] *= al;
        }

        float ls = 0.f;
#pragma unroll
        for (int j = 0; j < 4; ++j) {
          u16x4 pk;
#pragma unroll
          for (int r = 0; r < 4; ++r) {
            const float p = EXP2(__builtin_fmaf(s[j][r], SC, -mrow));
            ls += p;
            pk[r] = cvt_bf16(p);
          }
          *(u16x4*)&Pl[w][m16 * 64 + ((j * 16 + quad * 4) ^ sw)] = pk;
        }
        lsum += ls;

        bf16x8 pf[2];
        pf[0] = __builtin_bit_cast(
            bf16x8, *(const u16x8*)&Pl[w][m16 * 64 + ((quad * 8) ^ sw)]);
        pf[1] = __builtin_bit_cast(
            bf16x8, *(const u16x8*)&Pl[w][m16 * 64 + ((32 + quad * 8) ^ sw)]);
        __builtin_amdgcn_s_setprio(1);
#pragma unroll
        for (int t = 0; t < 4; ++t)
#pragma unroll
          for (int kk = 0; kk < 2; ++kk) {
            const bf16x8 vf = __builtin_bit_cast(
                bf16x8, *(const u16x8*)&Vl[buf][(t * 16 + m16) * 64 +
                                                ((kk * 32 + quad * 8) ^ sw)]);
            Oacc[t] = __builtin_amdgcn_mfma_f32_16x16x32_bf16(vf, pf[kk],
                                                              Oacc[t], 0, 0, 0);
          }
        __builtin_amdgcn_s_setprio(0);
        __syncthreads();
      }
    }

    float lt = lsum;
    lt += __shfl_xor(lt, 16, 64);
    lt += __shfl_xor(lt, 32, 64);
    const long row = bh * SEQ + qglob;
    float* Op = Opart + (long)h * NROWS * HEAD_DIM;
#pragma unroll
    for (int t = 0; t < 4; ++t)
      *(floatx4*)&Op[row * HEAD_DIM + t * 16 + quad * 4] = Oacc[t];
    if (quad == 0) mlpart[h * NROWS + row] = make_float2(mrow, lt);
  }
}

// ======== merge: combine the two kv-half partials per (bh,q) row ========
__global__ __launch_bounds__(256) void merge_attn(
    const float* __restrict__ Opart, const float2* __restrict__ mlpart,
    u16* __restrict__ Qy) {
  const int bid = blockIdx.x;
  const int bh = (bid & 7) | (((bid >> 10) & 3) << 3);  // 0..31
  const int chunk = (bid >> 3) & 127;                   // 0..127 (16 q each)
  const int r = threadIdx.x >> 4;
  const int d0 = (threadIdx.x & 15) * 4;
  const long row = (long)bh * SEQ + chunk * 16 + r;
  const float2 A = mlpart[row];
  const float2 B = mlpart[NROWS + row];
  const float M = fmaxf(A.x, B.x);
  const float w0 = EXP2(A.x - M), w1 = EXP2(B.x - M);
  const float inv = 1.f / (w0 * A.y + w1 * B.y);
  const floatx4 o0 = *(const floatx4*)&Opart[row * HEAD_DIM + d0];
  const floatx4 o1 =
      *(const floatx4*)&Opart[(long)NROWS * HEAD_DIM + row * HEAD_DIM + d0];
  u16x4 pk;
#pragma unroll
  for (int i = 0; i < 4; ++i)
    pk[i] = cvt_bf16((w0 * o0[i] + w1 * o1[i]) * inv);
  *(u16x4*)&Qy[row * HEAD_DIM + d0] = pk;
}

// ======== launch ========
extern "C" void kernel_launch(void* const* d_in, const int* in_sizes, int n_in,
                              void* d_out, int out_size, void* d_ws,
                              size_t ws_size, hipStream_t stream) {
  const float* x = (const float*)d_in[0];
  const float* w_attn = (const float*)d_in[1];
  const float* b_attn = (const float*)d_in[2];
  const float* w_proj = (const float*)d_in[3];
  const float* b_proj = (const float*)d_in[4];
  float* out = (float*)d_out;

  // ws: q 8 | k 8 | vT 8 | wT_a 6 | wT_p 2 | xb 8 | (48MB:) Opart 67 | ml 1
  char* ws = (char*)d_ws;
  const size_t SZ = (size_t)BATCH * N_HEAD * SEQ * HEAD_DIM * sizeof(u16);
  u16* q = (u16*)(ws);
  u16* k = (u16*)(ws + SZ);
  u16* vT = (u16*)(ws + 2 * SZ);
  u16* wT_a = (u16*)(ws + 3 * SZ);
  u16* wT_p = (u16*)(ws + 3 * SZ + (size_t)3 * N_EMBD * N_EMBD * sizeof(u16));
  u16* xb = (u16*)(ws + 3 * SZ + (size_t)4 * N_EMBD * N_EMBD * sizeof(u16));
  float* Opart = (float*)(ws + (size_t)48 * 1024 * 1024);
  float2* mlpart =
      (float2*)(ws + (size_t)48 * 1024 * 1024 +
                (size_t)2 * NROWS * HEAD_DIM * sizeof(float));

  prep<<<2048 + 4096, 256, 0, stream>>>(x, xb, w_attn, w_proj, wT_a, wT_p);

  gemm256<<<dim3(3 * N_EMBD / 256, M_ROWS / 256), 512, 128 * 1024, stream>>>(
      xb, wT_a, b_attn, q, k, vT);

  flash_attn<<<1024, 256, 0, stream>>>(q, k, vT, Opart, mlpart);

  merge_attn<<<4096, 256, 0, stream>>>(Opart, mlpart, q);

  gemm128<1><<<dim3(N_EMBD / 64, M_ROWS / 128), 256, 0, stream>>>(
      q, wT_p, b_proj, out, nullptr, nullptr, nullptr, N_EMBD, N_EMBD);
}

// Round 10
// 173.667 us; speedup vs baseline: 1.0474x; 1.0474x over previous
//
#include <hip/hip_runtime.h>

typedef unsigned short u16;
typedef u16 u16x4 __attribute__((ext_vector_type(4)));
typedef u16 u16x8 __attribute__((ext_vector_type(8)));
typedef __bf16 bf16x8 __attribute__((ext_vector_type(8)));
typedef float floatx4 __attribute__((ext_vector_type(4)));

#define N_EMBD 1024
#define N_HEAD 16
#define HEAD_DIM 64
#define SEQ 2048
#define BATCH 2
#define M_ROWS (BATCH * SEQ)  // 4096

typedef __attribute__((address_space(1))) const unsigned char ga_t;
typedef __attribute__((address_space(3))) unsigned char la_t;

#if __has_builtin(__builtin_amdgcn_exp2f)
#define EXP2(x) __builtin_amdgcn_exp2f(x)
#else
#define EXP2(x) exp2f(x)
#endif

// native gfx950 f32->bf16 (RNE), 1 instr
__device__ __forceinline__ u16 cvt_bf16(float f) {
  return __builtin_bit_cast(u16, (__bf16)f);
}

// ======== prep: convert x (blocks 0..2047) + transpose both weights ========
__global__ __launch_bounds__(256) void prep(const float* __restrict__ x,
                                            u16* __restrict__ xb,
                                            const float* __restrict__ wa,
                                            const float* __restrict__ wp,
                                            u16* __restrict__ outa,
                                            u16* __restrict__ outp) {
  const int bid = blockIdx.x;
  if (bid < 2048) {  // convert_x
    const long i = ((long)bid * 256 + threadIdx.x) * 8;
    const float4 f0 = *(const float4*)&x[i];
    const float4 f1 = *(const float4*)&x[i + 4];
    u16x8 p;
    p[0] = cvt_bf16(f0.x); p[1] = cvt_bf16(f0.y);
    p[2] = cvt_bf16(f0.z); p[3] = cvt_bf16(f0.w);
    p[4] = cvt_bf16(f1.x); p[5] = cvt_bf16(f1.y);
    p[6] = cvt_bf16(f1.z); p[7] = cvt_bf16(f1.w);
    *(u16x8*)&xb[i] = p;
    return;
  }
  // transpose: linearized (gx 0..127, gy 0..31); gx<96: w_attn, else w_proj
  __shared__ u16 tile[32][33];
  const int t = bid - 2048;
  const int gx = t & 127;
  const int gy = t >> 7;
  const int R = N_EMBD;
  const float* in;
  u16* out;
  int C, bx;
  if (gx < 96) {
    in = wa; out = outa; C = 3 * N_EMBD; bx = gx * 32;
  } else {
    in = wp; out = outp; C = N_EMBD; bx = (gx - 96) * 32;
  }
  const int by = gy * 32;
  const int tx = threadIdx.x & 31;
  const int ty = threadIdx.x >> 5;
#pragma unroll
  for (int j = 0; j < 32; j += 8)
    tile[ty + j][tx] = cvt_bf16(in[(long)(by + ty + j) * C + bx + tx]);
  __syncthreads();
#pragma unroll
  for (int j = 0; j < 32; j += 8)
    out[(long)(bx + ty + j) * R + by + tx] = tile[tx][ty + j];
}

// ======== gemm_qkv — 128x192 tile, BK=64, 8 waves, reg-pipelined ========
// Grid 16x32 = 512 blocks (2/CU exactly; %8==0), 512 threads, LDS 80KB
// dynamic (2 bufs: A 2x16K, B 2x24K). Schedule = round-9's verified one:
// ds_read ALL frags(kt) -> lgkmcnt(0)+barrier1 (buffer free) -> stage(kt+2)
// into freed buffer + vmcnt(5) (own kt+1 loads landed; kt+2 in flight ACROSS
// barrier) -> barrier2 (kt+1 visible) -> 24 MFMA from registers. 2 blocks/CU
// give cross-block TLP: one block MFMAs while the other waits at a barrier.
// Swizzle: slot^(row&7) both sides (rule #21); frag rows have row&7==m16&7.
#define GBK 64

__device__ __forceinline__ void stage192(const u16* __restrict__ A,
                                         const u16* __restrict__ Bt, int bm,
                                         int bn, int kt, int tid, u16* as,
                                         u16* bs) {
#pragma unroll
  for (int i = 0; i < 2; ++i) {  // A: 128 rows x 8 slots = 1024 chunks
    const int p = tid + 512 * i;
    const int row = p >> 3;              // 0..127
    const int sl = (p & 7) ^ (row & 7);  // inverse-swizzled 16B source slot
    const int wb = (i * 512 + (tid & 448)) * 8;  // wave-uniform dest (u16)
    __builtin_amdgcn_global_load_lds(
        (ga_t*)&A[(long)(bm + row) * N_EMBD + kt + sl * 8], (la_t*)&as[wb], 16,
        0, 0);
  }
#pragma unroll
  for (int i = 0; i < 3; ++i) {  // B: 192 rows x 8 slots = 1536 chunks
    const int p = tid + 512 * i;
    const int row = p >> 3;              // 0..191
    const int sl = (p & 7) ^ (row & 7);
    const int wb = (i * 512 + (tid & 448)) * 8;
    __builtin_amdgcn_global_load_lds(
        (ga_t*)&Bt[(long)(bn + row) * N_EMBD + kt + sl * 8], (la_t*)&bs[wb], 16,
        0, 0);
  }
}

__global__ __launch_bounds__(512, 4) void gemm_qkv(
    const u16* __restrict__ A, const u16* __restrict__ Bt,
    const float* __restrict__ bias, u16* __restrict__ qo, u16* __restrict__ ko,
    u16* __restrict__ vo) {
  extern __shared__ u16 smem[];
  u16* As = smem;                 // [2][128*64]
  u16* Bs = smem + 2 * 128 * 64;  // [2][192*64]
  const int tid = threadIdx.x;

  // bijective XCD swizzle (nwg = 512)
  const int nx = gridDim.x;  // 16
  const int nwg = nx * gridDim.y;
  int lin = blockIdx.y * nx + blockIdx.x;
  lin = (lin & 7) * (nwg >> 3) + (lin >> 3);
  const int bm = (lin / nx) * 128;
  const int bn = (lin % nx) * 192;

  const int w = tid >> 6;        // 0..7
  const int l = tid & 63;
  const int wm = (w >> 2) * 64;  // 2 M-rows of waves
  const int wn = (w & 3) * 48;   // 4 N-cols of waves (48 = mult of 16)
  const int m16 = l & 15;
  const int quad = l >> 4;
  const int rsw = m16 & 7;  // read-side XOR (frag row&7 == m16&7)

  floatx4 acc[4][3];
#pragma unroll
  for (int i = 0; i < 4; ++i)
#pragma unroll
    for (int j = 0; j < 3; ++j) acc[i][j] = (floatx4){0.f, 0.f, 0.f, 0.f};

  // prologue: tiles 0,1 in flight (5 loads each); wait tile 0
  stage192(A, Bt, bm, bn, 0, tid, As, Bs);
  stage192(A, Bt, bm, bn, GBK, tid, As + 128 * 64, Bs + 192 * 64);
  asm volatile("s_waitcnt vmcnt(5)" ::: "memory");
  __builtin_amdgcn_s_barrier();

  for (int kt = 0; kt < 16; ++kt) {
    u16* as = As + (kt & 1) * (128 * 64);
    u16* bs = Bs + (kt & 1) * (192 * 64);

    // all fragments of tile kt -> registers (14 x ds_read_b128)
    bf16x8 af[4][2], bf[3][2];
#pragma unroll
    for (int i = 0; i < 4; ++i)
#pragma unroll
      for (int kk = 0; kk < 2; ++kk)
        af[i][kk] = __builtin_bit_cast(
            bf16x8, *(const u16x8*)&as[(wm + i * 16 + m16) * 64 +
                                       (((kk * 4 + quad) ^ rsw) * 8)]);
#pragma unroll
    for (int j = 0; j < 3; ++j)
#pragma unroll
      for (int kk = 0; kk < 2; ++kk)
        bf[j][kk] = __builtin_bit_cast(
            bf16x8, *(const u16x8*)&bs[(wn + j * 16 + m16) * 64 +
                                       (((kk * 4 + quad) ^ rsw) * 8)]);
    asm volatile("s_waitcnt lgkmcnt(0)" ::: "memory");
    __builtin_amdgcn_s_barrier();  // all waves done READING this buffer

    if (kt + 2 < 16) {
      stage192(A, Bt, bm, bn, (kt + 2) * GBK, tid, as, bs);  // freed buffer
      asm volatile("s_waitcnt vmcnt(5)" ::: "memory");  // own kt+1 loads done
    } else {
      asm volatile("s_waitcnt vmcnt(0)" ::: "memory");
    }
    __builtin_amdgcn_s_barrier();  // tile kt+1 visible to every wave

    __builtin_amdgcn_s_setprio(1);
#pragma unroll
    for (int kk = 0; kk < 2; ++kk)  // kk outermost: no dependent MFMA pairs
#pragma unroll
      for (int i = 0; i < 4; ++i)
#pragma unroll
        for (int j = 0; j < 3; ++j)
          acc[i][j] = __builtin_amdgcn_mfma_f32_16x16x32_bf16(
              af[i][kk], bf[j][kk], acc[i][j], 0, 0, 0);
    __builtin_amdgcn_s_setprio(0);
  }

  // epilogue: scatter q/k (bf16 [B,H,T,D]) and vT ([B,H,D,T])
#pragma unroll
  for (int i = 0; i < 4; ++i) {
#pragma unroll
    for (int j = 0; j < 3; ++j) {
      const int col = bn + wn + j * 16 + m16;
      const float bv = bias[col];
      const int which = col >> 10;  // 0=q 1=k 2=v (uniform: 16-col frag
      const int cc = col & 1023;    //  is 16-aligned, never crosses 64)
      const int h = cc >> 6;
      const int dd = cc & 63;
      const int row0 = bm + wm + i * 16 + quad * 4;
      const int b = row0 >> 11;
      const int t0 = row0 & 2047;
      if (which == 2) {
        u16x4 pk;
#pragma unroll
        for (int r = 0; r < 4; ++r) pk[r] = cvt_bf16(acc[i][j][r] + bv);
        *(u16x4*)&vo[(((long)(b * N_HEAD + h)) * HEAD_DIM + dd) * SEQ + t0] =
            pk;
      } else {
        u16* dst = (which == 0) ? qo : ko;
#pragma unroll
        for (int r = 0; r < 4; ++r)
          dst[(((long)(b * N_HEAD + h)) * SEQ + t0 + r) * HEAD_DIM + dd] =
              cvt_bf16(acc[i][j][r] + bv);
      }
    }
  }
}

// ======== gemm128 MODE 1 — proj GEMM (unchanged round-8 triple-buffer) =====
#define BK 32

template <int MODE>
__device__ __forceinline__ void stage128(const u16* __restrict__ A,
                                         const u16* __restrict__ Bt, int bm,
                                         int bn, int kt, int K, int tid,
                                         u16* as, u16* bs) {
  const int w = tid >> 6;
  const int l = tid & 63;
  const int lrow = l >> 2;  // 0..15
#pragma unroll
  for (int p = 0; p < 2; ++p) {  // A: 128 rows
    const int arow = p * 64 + w * 16;
    const int row = arow + lrow;
    const int sl = (l & 3) ^ ((row >> 1) & 3);
    long gA;
    if (MODE == 0) {
      gA = (long)(bm + row) * K + kt + sl * 8;
    } else {
      const int m = bm + row;
      const int b = m >> 11, t = m & 2047;
      const int k0 = kt + sl * 8;
      const int head = k0 >> 6, dd = k0 & 63;
      gA = (((long)(b * N_HEAD + head)) * SEQ + t) * HEAD_DIM + dd;
    }
    __builtin_amdgcn_global_load_lds((ga_t*)(A + gA), (la_t*)&as[arow * BK],
                                     16, 0, 0);
  }
  constexpr int TN = (MODE == 1) ? 64 : 128;
#pragma unroll
  for (int p = 0; p < TN / 64; ++p) {  // B: TN rows
    const int arow = p * 64 + w * 16;
    const int row = arow + lrow;
    const int sl = (l & 3) ^ ((row >> 1) & 3);
    const long gB = (long)(bn + row) * K + kt + sl * 8;
    __builtin_amdgcn_global_load_lds((ga_t*)(Bt + gB), (la_t*)&bs[arow * BK],
                                     16, 0, 0);
  }
}

template <int MODE>
__global__ __launch_bounds__(256) void gemm128(
    const u16* __restrict__ A, const u16* __restrict__ Bt,
    const float* __restrict__ bias, float* __restrict__ out,
    u16* __restrict__ qo, u16* __restrict__ ko, u16* __restrict__ vo, int N,
    int K) {
  constexpr int TN = (MODE == 1) ? 64 : 128;
  constexpr int NJ = TN / 32;
  __shared__ u16 As[3][128 * BK];
  __shared__ u16 Bs[3][TN * BK];
  const int tid = threadIdx.x;

  const int nx = gridDim.x;
  const int nwg = nx * gridDim.y;
  int lin = blockIdx.y * nx + blockIdx.x;
  lin = (lin & 7) * (nwg >> 3) + (lin >> 3);
  const int bm = (lin / nx) * 128;
  const int bn = (lin % nx) * TN;

  const int w = tid >> 6;
  const int l = tid & 63;
  const int wm = (w >> 1) * 64;
  const int wn = (w & 1) * (TN / 2);
  const int m16 = l & 15;
  const int quad = l >> 4;
  const int ksw = (quad ^ ((m16 >> 1) & 3)) * 8;

  floatx4 acc[4][NJ];
#pragma unroll
  for (int i = 0; i < 4; ++i)
#pragma unroll
    for (int j = 0; j < NJ; ++j) acc[i][j] = (floatx4){0.f, 0.f, 0.f, 0.f};

  const int nk = K / BK;
  stage128<MODE>(A, Bt, bm, bn, 0, K, tid, As[0], Bs[0]);
  stage128<MODE>(A, Bt, bm, bn, BK, K, tid, As[1], Bs[1]);

  u16 *a0 = As[0], *a1 = As[1], *a2 = As[2];
  u16 *b0 = Bs[0], *b1 = Bs[1], *b2 = Bs[2];

  for (int t = 0; t < nk; ++t) {
    if (t + 1 < nk) {
      if constexpr (MODE == 0)
        asm volatile("s_waitcnt vmcnt(4)" ::: "memory");
      else
        asm volatile("s_waitcnt vmcnt(3)" ::: "memory");
    } else {
      asm volatile("s_waitcnt vmcnt(0)" ::: "memory");
    }
    __builtin_amdgcn_s_barrier();

    if (t + 2 < nk)
      stage128<MODE>(A, Bt, bm, bn, (t + 2) * BK, K, tid, a2, b2);

    bf16x8 af[4], bfr[NJ];
#pragma unroll
    for (int i = 0; i < 4; ++i)
      af[i] = __builtin_bit_cast(
          bf16x8, *(const u16x8*)&a0[(wm + i * 16 + m16) * BK + ksw]);
#pragma unroll
    for (int j = 0; j < NJ; ++j)
      bfr[j] = __builtin_bit_cast(
          bf16x8, *(const u16x8*)&b0[(wn + j * 16 + m16) * BK + ksw]);
#pragma unroll
    for (int i = 0; i < 4; ++i)
#pragma unroll
      for (int j = 0; j < NJ; ++j)
        acc[i][j] = __builtin_amdgcn_mfma_f32_16x16x32_bf16(af[i], bfr[j],
                                                            acc[i][j], 0, 0, 0);
    u16* ta = a0; a0 = a1; a1 = a2; a2 = ta;
    u16* tb = b0; b0 = b1; b1 = b2; b2 = tb;
  }

#pragma unroll
  for (int i = 0; i < 4; ++i) {
#pragma unroll
    for (int j = 0; j < NJ; ++j) {
      const int col = bn + wn + j * 16 + m16;
      const float bv = bias[col];
      if (MODE == 1) {
#pragma unroll
        for (int r = 0; r < 4; ++r) {
          const int row = bm + wm + i * 16 + quad * 4 + r;
          out[(long)row * N_EMBD + col] = acc[i][j][r] + bv;
        }
      } else {
        const int which = col >> 10;
        const int cc = col & 1023;
        const int h = cc >> 6;
        const int dd = cc & 63;
        const int row0 = bm + wm + i * 16 + quad * 4;
        const int b = row0 >> 11;
        const int t0 = row0 & 2047;
        if (which == 2) {
          u16x4 pk;
#pragma unroll
          for (int r = 0; r < 4; ++r) pk[r] = cvt_bf16(acc[i][j][r] + bv);
          *(u16x4*)&vo[(((long)(b * N_HEAD + h)) * HEAD_DIM + dd) * SEQ + t0] =
              pk;
        } else {
          u16* dst = (which == 0) ? qo : ko;
#pragma unroll
          for (int r = 0; r < 4; ++r)
            dst[(((long)(b * N_HEAD + h)) * SEQ + t0 + r) * HEAD_DIM + dd] =
                cvt_bf16(acc[i][j][r] + bv);
        }
      }
    }
  }
}

// ======== flash attention — uniform blocks: q-tile pair + KV-half split ====
// (unchanged from round 8)
#define BQ 64
#define BKV 64
#define LOG2E 1.44269504f
#define NQT (SEQ / BQ)      // 32 q-tiles
#define NROWS (32 * SEQ)    // 65536 (bh, q) rows

__device__ __forceinline__ void stage_kv(const u16* __restrict__ K,
                                         const u16* __restrict__ Vt, long bh,
                                         int kt, int tid, u16* kl, u16* vl) {
#pragma unroll
  for (int i = 0; i < 2; ++i) {
    const int p = tid + 256 * i;
    const int row = p >> 3;                    // K: key   V: d
    const int slot = (p & 7) ^ (row & 7);      // swizzled 16B source slot
    const int wb = (i * 256 + (tid & 192)) * 8;  // wave-uniform dest (u16)
    __builtin_amdgcn_global_load_lds(
        (ga_t*)&K[(bh * SEQ + kt + row) * HEAD_DIM + slot * 8], (la_t*)&kl[wb],
        16, 0, 0);
    __builtin_amdgcn_global_load_lds(
        (ga_t*)&Vt[(bh * HEAD_DIM + row) * SEQ + kt + slot * 8], (la_t*)&vl[wb],
        16, 0, 0);
  }
}

__global__ __launch_bounds__(256, 4) void flash_attn(
    const u16* __restrict__ Qy, const u16* __restrict__ K,
    const u16* __restrict__ Vt, float* __restrict__ Opart,
    float2* __restrict__ mlpart) {
  const int id = blockIdx.x;
  const int a = id >> 6;        // 0..15: pair index
  const int h = (id >> 5) & 1;  // kv-half
  const long bh = id & 31;      // id%8 = bh%8 -> XCD affinity
  const int tid = threadIdx.x;
  const int w = tid >> 6;
  const int l = tid & 63;
  const int m16 = l & 15;
  const int quad = l >> 4;

  __shared__ u16 Kl[2][BKV * 64];
  __shared__ u16 Vl[2][64 * BKV];
  __shared__ u16 Pl[4][16 * 64];

  const float SC = 0.125f * LOG2E;
  const int sw = (m16 & 7) << 3;

  for (int ph = 0; ph < 2; ++ph) {
    const int iq = ph ? (31 - a) : a;
    const int na = iq + 1;
    const int mid = (na + 1) >> 1;
    const int s0 = h ? mid : 0;
    const int e0 = h ? na : mid;
    const int qglob = iq * BQ + w * 16 + m16;

    bf16x8 qf[2];
    {
      const u16* qrow = Qy + (bh * SEQ + qglob) * HEAD_DIM;
      qf[0] = __builtin_bit_cast(bf16x8, *(const u16x8*)&qrow[quad * 8]);
      qf[1] = __builtin_bit_cast(bf16x8, *(const u16x8*)&qrow[32 + quad * 8]);
    }

    floatx4 Oacc[4];
#pragma unroll
    for (int t = 0; t < 4; ++t) Oacc[t] = (floatx4){0.f, 0.f, 0.f, 0.f};
    float mrow = -1e30f, lsum = 0.f;

    if (s0 < e0) {
      stage_kv(K, Vt, bh, s0 * BKV, tid, Kl[0], Vl[0]);
      __syncthreads();

      for (int it = s0; it < e0; ++it) {
        const int buf = (it - s0) & 1;
        const int kt = it * BKV;
        if (it + 1 < e0)
          stage_kv(K, Vt, bh, kt + BKV, tid, Kl[buf ^ 1], Vl[buf ^ 1]);

        floatx4 s[4];
#pragma unroll
        for (int j = 0; j < 4; ++j) s[j] = (floatx4){0.f, 0.f, 0.f, 0.f};
        __builtin_amdgcn_s_setprio(1);
#pragma unroll
        for (int j = 0; j < 4; ++j)
#pragma unroll
          for (int kk = 0; kk < 2; ++kk) {
            const bf16x8 kf = __builtin_bit_cast(
                bf16x8, *(const u16x8*)&Kl[buf][(j * 16 + m16) * 64 +
                                                ((kk * 32 + quad * 8) ^ sw)]);
            s[j] = __builtin_amdgcn_mfma_f32_16x16x32_bf16(kf, qf[kk], s[j], 0,
                                                           0, 0);
          }
        __builtin_amdgcn_s_setprio(0);
        if (it == na - 1) {
#pragma unroll
          for (int j = 0; j < 4; ++j) {
            const int key0 = kt + j * 16 + quad * 4;
#pragma unroll
            for (int r = 0; r < 4; ++r)
              if (key0 + r > qglob) s[j][r] = -1e30f;
          }
        }

        float tm = s[0][0];
#pragma unroll
        for (int j = 0; j < 4; ++j)
#pragma unroll
          for (int r = 0; r < 4; ++r)
            if (j + r) tm = fmaxf(tm, s[j][r]);
        tm = fmaxf(tm, __shfl_xor(tm, 16, 64));
        tm = fmaxf(tm, __shfl_xor(tm, 32, 64));
        const float pm = tm * SC;
        if (!__all(pm <= mrow + 4.f)) {
          const float mn = fmaxf(mrow, pm);
          const float al = EXP2(mrow - mn);
          mrow = mn;
          lsum *= al;
#pragma unroll
          for (int t = 0; t < 4; ++t)
#pragma unroll
            for (int r = 0; r < 4; ++r) Oacc[t][r] *= al;
        }

        float ls = 0.f;
#pragma unroll
        for (int j = 0; j < 4; ++j) {
          u16x4 pk;
#pragma unroll
          for (int r = 0; r < 4; ++r) {
            const float p = EXP2(__builtin_fmaf(s[j][r], SC, -mrow));
            ls += p;
            pk[r] = cvt_bf16(p);
          }
          *(u16x4*)&Pl[w][m16 * 64 + ((j * 16 + quad * 4) ^ sw)] = pk;
        }
        lsum += ls;

        bf16x8 pf[2];
        pf[0] = __builtin_bit_cast(
            bf16x8, *(const u16x8*)&Pl[w][m16 * 64 + ((quad * 8) ^ sw)]);
        pf[1] = __builtin_bit_cast(
            bf16x8, *(const u16x8*)&Pl[w][m16 * 64 + ((32 + quad * 8) ^ sw)]);
        __builtin_amdgcn_s_setprio(1);
#pragma unroll
        for (int t = 0; t < 4; ++t)
#pragma unroll
          for (int kk = 0; kk < 2; ++kk) {
            const bf16x8 vf = __builtin_bit_cast(
                bf16x8, *(const u16x8*)&Vl[buf][(t * 16 + m16) * 64 +
                                                ((kk * 32 + quad * 8) ^ sw)]);
            Oacc[t] = __builtin_amdgcn_mfma_f32_16x16x32_bf16(vf, pf[kk],
                                                              Oacc[t], 0, 0, 0);
          }
        __builtin_amdgcn_s_setprio(0);
        __syncthreads();
      }
    }

    float lt = lsum;
    lt += __shfl_xor(lt, 16, 64);
    lt += __shfl_xor(lt, 32, 64);
    const long row = bh * SEQ + qglob;
    float* Op = Opart + (long)h * NROWS * HEAD_DIM;
#pragma unroll
    for (int t = 0; t < 4; ++t)
      *(floatx4*)&Op[row * HEAD_DIM + t * 16 + quad * 4] = Oacc[t];
    if (quad == 0) mlpart[h * NROWS + row] = make_float2(mrow, lt);
  }
}

// ======== merge: combine the two kv-half partials per (bh,q) row ========
__global__ __launch_bounds__(256) void merge_attn(
    const float* __restrict__ Opart, const float2* __restrict__ mlpart,
    u16* __restrict__ Qy) {
  const int bid = blockIdx.x;
  const int bh = (bid & 7) | (((bid >> 10) & 3) << 3);  // 0..31
  const int chunk = (bid >> 3) & 127;                   // 0..127 (16 q each)
  const int r = threadIdx.x >> 4;
  const int d0 = (threadIdx.x & 15) * 4;
  const long row = (long)bh * SEQ + chunk * 16 + r;
  const float2 A = mlpart[row];
  const float2 B = mlpart[NROWS + row];
  const float M = fmaxf(A.x, B.x);
  const float w0 = EXP2(A.x - M), w1 = EXP2(B.x - M);
  const float inv = 1.f / (w0 * A.y + w1 * B.y);
  const floatx4 o0 = *(const floatx4*)&Opart[row * HEAD_DIM + d0];
  const floatx4 o1 =
      *(const floatx4*)&Opart[(long)NROWS * HEAD_DIM + row * HEAD_DIM + d0];
  u16x4 pk;
#pragma unroll
  for (int i = 0; i < 4; ++i)
    pk[i] = cvt_bf16((w0 * o0[i] + w1 * o1[i]) * inv);
  *(u16x4*)&Qy[row * HEAD_DIM + d0] = pk;
}

// ======== launch ========
extern "C" void kernel_launch(void* const* d_in, const int* in_sizes, int n_in,
                              void* d_out, int out_size, void* d_ws,
                              size_t ws_size, hipStream_t stream) {
  const float* x = (const float*)d_in[0];
  const float* w_attn = (const float*)d_in[1];
  const float* b_attn = (const float*)d_in[2];
  const float* w_proj = (const float*)d_in[3];
  const float* b_proj = (const float*)d_in[4];
  float* out = (float*)d_out;

  // ws: q 8 | k 8 | vT 8 | wT_a 6 | wT_p 2 | xb 8 | (48MB:) Opart 67 | ml 1
  char* ws = (char*)d_ws;
  const size_t SZ = (size_t)BATCH * N_HEAD * SEQ * HEAD_DIM * sizeof(u16);
  u16* q = (u16*)(ws);
  u16* k = (u16*)(ws + SZ);
  u16* vT = (u16*)(ws + 2 * SZ);
  u16* wT_a = (u16*)(ws + 3 * SZ);
  u16* wT_p = (u16*)(ws + 3 * SZ + (size_t)3 * N_EMBD * N_EMBD * sizeof(u16));
  u16* xb = (u16*)(ws + 3 * SZ + (size_t)4 * N_EMBD * N_EMBD * sizeof(u16));
  float* Opart = (float*)(ws + (size_t)48 * 1024 * 1024);
  float2* mlpart =
      (float2*)(ws + (size_t)48 * 1024 * 1024 +
                (size_t)2 * NROWS * HEAD_DIM * sizeof(float));

  prep<<<2048 + 4096, 256, 0, stream>>>(x, xb, w_attn, w_proj, wT_a, wT_p);

  gemm_qkv<<<dim3(3 * N_EMBD / 192, M_ROWS / 128), 512,
             (2 * 128 * 64 + 2 * 192 * 64) * sizeof(u16), stream>>>(
      xb, wT_a, b_attn, q, k, vT);

  flash_attn<<<1024, 256, 0, stream>>>(q, k, vT, Opart, mlpart);

  merge_attn<<<4096, 256, 0, stream>>>(Opart, mlpart, q);

  gemm128<1><<<dim3(N_EMBD / 64, M_ROWS / 128), 256, 0, stream>>>(
      q, wT_p, b_proj, out, nullptr, nullptr, nullptr, N_EMBD, N_EMBD);
}

// Round 11
// 171.005 us; speedup vs baseline: 1.0637x; 1.0156x over previous
//
#include <hip/hip_runtime.h>

typedef unsigned short u16;
typedef u16 u16x4 __attribute__((ext_vector_type(4)));
typedef u16 u16x8 __attribute__((ext_vector_type(8)));
typedef __bf16 bf16x8 __attribute__((ext_vector_type(8)));
typedef float floatx4 __attribute__((ext_vector_type(4)));

#define N_EMBD 1024
#define N_HEAD 16
#define HEAD_DIM 64
#define SEQ 2048
#define BATCH 2
#define M_ROWS (BATCH * SEQ)  // 4096

typedef __attribute__((address_space(1))) const unsigned char ga_t;
typedef __attribute__((address_space(3))) unsigned char la_t;

#if __has_builtin(__builtin_amdgcn_exp2f)
#define EXP2(x) __builtin_amdgcn_exp2f(x)
#else
#define EXP2(x) exp2f(x)
#endif

// native gfx950 f32->bf16 (RNE), 1 instr
__device__ __forceinline__ u16 cvt_bf16(float f) {
  return __builtin_bit_cast(u16, (__bf16)f);
}

// ======== prep: convert x (blocks 0..2047) + transpose both weights ========
__global__ __launch_bounds__(256) void prep(const float* __restrict__ x,
                                            u16* __restrict__ xb,
                                            const float* __restrict__ wa,
                                            const float* __restrict__ wp,
                                            u16* __restrict__ outa,
                                            u16* __restrict__ outp) {
  const int bid = blockIdx.x;
  if (bid < 2048) {  // convert_x
    const long i = ((long)bid * 256 + threadIdx.x) * 8;
    const float4 f0 = *(const float4*)&x[i];
    const float4 f1 = *(const float4*)&x[i + 4];
    u16x8 p;
    p[0] = cvt_bf16(f0.x); p[1] = cvt_bf16(f0.y);
    p[2] = cvt_bf16(f0.z); p[3] = cvt_bf16(f0.w);
    p[4] = cvt_bf16(f1.x); p[5] = cvt_bf16(f1.y);
    p[6] = cvt_bf16(f1.z); p[7] = cvt_bf16(f1.w);
    *(u16x8*)&xb[i] = p;
    return;
  }
  // transpose: linearized (gx 0..127, gy 0..31); gx<96: w_attn, else w_proj
  __shared__ u16 tile[32][33];
  const int t = bid - 2048;
  const int gx = t & 127;
  const int gy = t >> 7;
  const int R = N_EMBD;
  const float* in;
  u16* out;
  int C, bx;
  if (gx < 96) {
    in = wa; out = outa; C = 3 * N_EMBD; bx = gx * 32;
  } else {
    in = wp; out = outp; C = N_EMBD; bx = (gx - 96) * 32;
  }
  const int by = gy * 32;
  const int tx = threadIdx.x & 31;
  const int ty = threadIdx.x >> 5;
#pragma unroll
  for (int j = 0; j < 32; j += 8)
    tile[ty + j][tx] = cvt_bf16(in[(long)(by + ty + j) * C + bx + tx]);
  __syncthreads();
#pragma unroll
  for (int j = 0; j < 32; j += 8)
    out[(long)(bx + ty + j) * R + by + tx] = tile[tx][ty + j];
}

// ======== gemm_qkv — 128x192 tile, BK=64, 8 waves, reg-pipelined ========
// (unchanged from round 10 — verified; ~30-33 us)
#define GBK 64

__device__ __forceinline__ void stage192(const u16* __restrict__ A,
                                         const u16* __restrict__ Bt, int bm,
                                         int bn, int kt, int tid, u16* as,
                                         u16* bs) {
#pragma unroll
  for (int i = 0; i < 2; ++i) {  // A: 128 rows x 8 slots = 1024 chunks
    const int p = tid + 512 * i;
    const int row = p >> 3;              // 0..127
    const int sl = (p & 7) ^ (row & 7);  // inverse-swizzled 16B source slot
    const int wb = (i * 512 + (tid & 448)) * 8;  // wave-uniform dest (u16)
    __builtin_amdgcn_global_load_lds(
        (ga_t*)&A[(long)(bm + row) * N_EMBD + kt + sl * 8], (la_t*)&as[wb], 16,
        0, 0);
  }
#pragma unroll
  for (int i = 0; i < 3; ++i) {  // B: 192 rows x 8 slots = 1536 chunks
    const int p = tid + 512 * i;
    const int row = p >> 3;              // 0..191
    const int sl = (p & 7) ^ (row & 7);
    const int wb = (i * 512 + (tid & 448)) * 8;
    __builtin_amdgcn_global_load_lds(
        (ga_t*)&Bt[(long)(bn + row) * N_EMBD + kt + sl * 8], (la_t*)&bs[wb], 16,
        0, 0);
  }
}

__global__ __launch_bounds__(512, 4) void gemm_qkv(
    const u16* __restrict__ A, const u16* __restrict__ Bt,
    const float* __restrict__ bias, u16* __restrict__ qo, u16* __restrict__ ko,
    u16* __restrict__ vo) {
  extern __shared__ u16 smem[];
  u16* As = smem;                 // [2][128*64]
  u16* Bs = smem + 2 * 128 * 64;  // [2][192*64]
  const int tid = threadIdx.x;

  // bijective XCD swizzle (nwg = 512)
  const int nx = gridDim.x;  // 16
  const int nwg = nx * gridDim.y;
  int lin = blockIdx.y * nx + blockIdx.x;
  lin = (lin & 7) * (nwg >> 3) + (lin >> 3);
  const int bm = (lin / nx) * 128;
  const int bn = (lin % nx) * 192;

  const int w = tid >> 6;        // 0..7
  const int l = tid & 63;
  const int wm = (w >> 2) * 64;  // 2 M-rows of waves
  const int wn = (w & 3) * 48;   // 4 N-cols of waves (48 = mult of 16)
  const int m16 = l & 15;
  const int quad = l >> 4;
  const int rsw = m16 & 7;  // read-side XOR (frag row&7 == m16&7)

  floatx4 acc[4][3];
#pragma unroll
  for (int i = 0; i < 4; ++i)
#pragma unroll
    for (int j = 0; j < 3; ++j) acc[i][j] = (floatx4){0.f, 0.f, 0.f, 0.f};

  // prologue: tiles 0,1 in flight (5 loads each); wait tile 0
  stage192(A, Bt, bm, bn, 0, tid, As, Bs);
  stage192(A, Bt, bm, bn, GBK, tid, As + 128 * 64, Bs + 192 * 64);
  asm volatile("s_waitcnt vmcnt(5)" ::: "memory");
  __builtin_amdgcn_s_barrier();

  for (int kt = 0; kt < 16; ++kt) {
    u16* as = As + (kt & 1) * (128 * 64);
    u16* bs = Bs + (kt & 1) * (192 * 64);

    // all fragments of tile kt -> registers (14 x ds_read_b128)
    bf16x8 af[4][2], bf[3][2];
#pragma unroll
    for (int i = 0; i < 4; ++i)
#pragma unroll
      for (int kk = 0; kk < 2; ++kk)
        af[i][kk] = __builtin_bit_cast(
            bf16x8, *(const u16x8*)&as[(wm + i * 16 + m16) * 64 +
                                       (((kk * 4 + quad) ^ rsw) * 8)]);
#pragma unroll
    for (int j = 0; j < 3; ++j)
#pragma unroll
      for (int kk = 0; kk < 2; ++kk)
        bf[j][kk] = __builtin_bit_cast(
            bf16x8, *(const u16x8*)&bs[(wn + j * 16 + m16) * 64 +
                                       (((kk * 4 + quad) ^ rsw) * 8)]);
    asm volatile("s_waitcnt lgkmcnt(0)" ::: "memory");
    __builtin_amdgcn_s_barrier();  // all waves done READING this buffer

    if (kt + 2 < 16) {
      stage192(A, Bt, bm, bn, (kt + 2) * GBK, tid, as, bs);  // freed buffer
      asm volatile("s_waitcnt vmcnt(5)" ::: "memory");  // own kt+1 loads done
    } else {
      asm volatile("s_waitcnt vmcnt(0)" ::: "memory");
    }
    __builtin_amdgcn_s_barrier();  // tile kt+1 visible to every wave

    __builtin_amdgcn_s_setprio(1);
#pragma unroll
    for (int kk = 0; kk < 2; ++kk)  // kk outermost: no dependent MFMA pairs
#pragma unroll
      for (int i = 0; i < 4; ++i)
#pragma unroll
        for (int j = 0; j < 3; ++j)
          acc[i][j] = __builtin_amdgcn_mfma_f32_16x16x32_bf16(
              af[i][kk], bf[j][kk], acc[i][j], 0, 0, 0);
    __builtin_amdgcn_s_setprio(0);
  }

  // epilogue: scatter q/k (bf16 [B,H,T,D]) and vT ([B,H,D,T])
#pragma unroll
  for (int i = 0; i < 4; ++i) {
#pragma unroll
    for (int j = 0; j < 3; ++j) {
      const int col = bn + wn + j * 16 + m16;
      const float bv = bias[col];
      const int which = col >> 10;  // 0=q 1=k 2=v (uniform: 16-col frag
      const int cc = col & 1023;    //  is 16-aligned, never crosses 64)
      const int h = cc >> 6;
      const int dd = cc & 63;
      const int row0 = bm + wm + i * 16 + quad * 4;
      const int b = row0 >> 11;
      const int t0 = row0 & 2047;
      if (which == 2) {
        u16x4 pk;
#pragma unroll
        for (int r = 0; r < 4; ++r) pk[r] = cvt_bf16(acc[i][j][r] + bv);
        *(u16x4*)&vo[(((long)(b * N_HEAD + h)) * HEAD_DIM + dd) * SEQ + t0] =
            pk;
      } else {
        u16* dst = (which == 0) ? qo : ko;
#pragma unroll
        for (int r = 0; r < 4; ++r)
          dst[(((long)(b * N_HEAD + h)) * SEQ + t0 + r) * HEAD_DIM + dd] =
              cvt_bf16(acc[i][j][r] + bv);
      }
    }
  }
}

// ======== gemm_proj — 128x64 tile, BK=64, 4 waves, reg-pipelined ========
// Same verified schedule as gemm_qkv, 256 threads. Grid 16x32 = 512 blocks
// (%8==0), static LDS 48KB. A = q-buffer remap ([B,H,T,D] -> [m][k]); at
// BK=64 the remap is clean: head = kt>>6 (wave-uniform), dd = sl*8.
#define PBK 64

__device__ __forceinline__ void stage_proj(const u16* __restrict__ A,
                                           const u16* __restrict__ Bt, int bm,
                                           int bn, int kt, int tid, u16* as,
                                           u16* bs) {
  const int head = kt >> 6;  // kt is a multiple of 64
#pragma unroll
  for (int i = 0; i < 4; ++i) {  // A: 128 rows x 8 slots = 1024 chunks
    const int p = tid + 256 * i;
    const int row = p >> 3;              // 0..127
    const int sl = (p & 7) ^ (row & 7);  // inverse-swizzled 16B source slot
    const int wb = (i * 256 + (tid & 192)) * 8;  // wave-uniform dest (u16)
    const int m = bm + row;
    const int b = m >> 11, t = m & 2047;
    __builtin_amdgcn_global_load_lds(
        (ga_t*)&A[(((long)(b * N_HEAD + head)) * SEQ + t) * HEAD_DIM + sl * 8],
        (la_t*)&as[wb], 16, 0, 0);
  }
#pragma unroll
  for (int i = 0; i < 2; ++i) {  // B: 64 rows x 8 slots = 512 chunks
    const int p = tid + 256 * i;
    const int row = p >> 3;  // 0..63
    const int sl = (p & 7) ^ (row & 7);
    const int wb = (i * 256 + (tid & 192)) * 8;
    __builtin_amdgcn_global_load_lds(
        (ga_t*)&Bt[(long)(bn + row) * N_EMBD + kt + sl * 8], (la_t*)&bs[wb], 16,
        0, 0);
  }
}

__global__ __launch_bounds__(256) void gemm_proj(const u16* __restrict__ A,
                                                 const u16* __restrict__ Bt,
                                                 const float* __restrict__ bias,
                                                 float* __restrict__ out) {
  __shared__ u16 As[2][128 * 64];  // 32 KB
  __shared__ u16 Bs[2][64 * 64];   // 16 KB
  const int tid = threadIdx.x;

  // bijective XCD swizzle (nwg = 512)
  const int nx = gridDim.x;  // 16
  const int nwg = nx * gridDim.y;
  int lin = blockIdx.y * nx + blockIdx.x;
  lin = (lin & 7) * (nwg >> 3) + (lin >> 3);
  const int bm = (lin / nx) * 128;
  const int bn = (lin % nx) * 64;

  const int w = tid >> 6;        // 0..3
  const int l = tid & 63;
  const int wm = (w >> 1) * 64;  // {0,64}
  const int wn = (w & 1) * 32;   // {0,32}
  const int m16 = l & 15;
  const int quad = l >> 4;
  const int rsw = m16 & 7;

  floatx4 acc[4][2];
#pragma unroll
  for (int i = 0; i < 4; ++i)
#pragma unroll
    for (int j = 0; j < 2; ++j) acc[i][j] = (floatx4){0.f, 0.f, 0.f, 0.f};

  // prologue: tiles 0,1 in flight (6 loads each); wait tile 0
  stage_proj(A, Bt, bm, bn, 0, tid, As[0], Bs[0]);
  stage_proj(A, Bt, bm, bn, PBK, tid, As[1], Bs[1]);
  asm volatile("s_waitcnt vmcnt(6)" ::: "memory");
  __builtin_amdgcn_s_barrier();

  for (int kt = 0; kt < 16; ++kt) {
    u16* as = As[kt & 1];
    u16* bs = Bs[kt & 1];

    bf16x8 af[4][2], bf[2][2];
#pragma unroll
    for (int i = 0; i < 4; ++i)
#pragma unroll
      for (int kk = 0; kk < 2; ++kk)
        af[i][kk] = __builtin_bit_cast(
            bf16x8, *(const u16x8*)&as[(wm + i * 16 + m16) * 64 +
                                       (((kk * 4 + quad) ^ rsw) * 8)]);
#pragma unroll
    for (int j = 0; j < 2; ++j)
#pragma unroll
      for (int kk = 0; kk < 2; ++kk)
        bf[j][kk] = __builtin_bit_cast(
            bf16x8, *(const u16x8*)&bs[(wn + j * 16 + m16) * 64 +
                                       (((kk * 4 + quad) ^ rsw) * 8)]);
    asm volatile("s_waitcnt lgkmcnt(0)" ::: "memory");
    __builtin_amdgcn_s_barrier();  // all waves done READING this buffer

    if (kt + 2 < 16) {
      stage_proj(A, Bt, bm, bn, (kt + 2) * PBK, tid, as, bs);
      asm volatile("s_waitcnt vmcnt(6)" ::: "memory");  // own kt+1 loads done
    } else {
      asm volatile("s_waitcnt vmcnt(0)" ::: "memory");
    }
    __builtin_amdgcn_s_barrier();  // tile kt+1 visible to every wave

    __builtin_amdgcn_s_setprio(1);
#pragma unroll
    for (int kk = 0; kk < 2; ++kk)
#pragma unroll
      for (int i = 0; i < 4; ++i)
#pragma unroll
        for (int j = 0; j < 2; ++j)
          acc[i][j] = __builtin_amdgcn_mfma_f32_16x16x32_bf16(
              af[i][kk], bf[j][kk], acc[i][j], 0, 0, 0);
    __builtin_amdgcn_s_setprio(0);
  }

  // epilogue: fp32 out + bias
#pragma unroll
  for (int i = 0; i < 4; ++i) {
#pragma unroll
    for (int j = 0; j < 2; ++j) {
      const int col = bn + wn + j * 16 + m16;
      const float bv = bias[col];
#pragma unroll
      for (int r = 0; r < 4; ++r) {
        const int row = bm + wm + i * 16 + quad * 4 + r;
        out[(long)row * N_EMBD + col] = acc[i][j][r] + bv;
      }
    }
  }
}

// ======== flash attention — round-5 structure (balanced CU schedule) ======
// 1024 blocks (32 q-tiles x 32 bh), 256 threads, LDS 40960 B -> exactly
// 4 blocks/CU. Map id=(r*256+c), g=c>>5, bh=c&31: iq = {31-g,16+g,15-g,g}[r]
// -> every CU's four co-resident blocks total 66 tile-iters (balanced).
// id%8 = bh%8 keeps each head's KV on one XCD's L2. Direct Qy write (the
// round-6 KV-split+merge A/B'd to zero gain and cost a 5-6us dispatch).
#define BQ 64
#define BKV 64
#define LOG2E 1.44269504f
#define NQT (SEQ / BQ)  // 32 q-tiles

__device__ __forceinline__ void stage_kv(const u16* __restrict__ K,
                                         const u16* __restrict__ Vt, long bh,
                                         int kt, int tid, u16* kl, u16* vl) {
#pragma unroll
  for (int i = 0; i < 2; ++i) {
    const int p = tid + 256 * i;
    const int row = p >> 3;                    // K: key   V: d
    const int slot = (p & 7) ^ (row & 7);      // swizzled 16B source slot
    const int wb = (i * 256 + (tid & 192)) * 8;  // wave-uniform dest (u16)
    __builtin_amdgcn_global_load_lds(
        (ga_t*)&K[(bh * SEQ + kt + row) * HEAD_DIM + slot * 8], (la_t*)&kl[wb],
        16, 0, 0);
    __builtin_amdgcn_global_load_lds(
        (ga_t*)&Vt[(bh * HEAD_DIM + row) * SEQ + kt + slot * 8], (la_t*)&vl[wb],
        16, 0, 0);
  }
}

__global__ __launch_bounds__(256, 4) void flash_attn(
    u16* __restrict__ Qy, const u16* __restrict__ K,
    const u16* __restrict__ Vt) {
  const int id = blockIdx.x;
  const int r = id >> 8;  // 0..3  (co-CU class = id & 255)
  const int c = id & 255;
  const int g = c >> 5;   // 0..7
  const long bh = c & 31;
  const int iq = (r == 0) ? (31 - g)
               : (r == 1) ? (16 + g)
               : (r == 2) ? (15 - g)
                          : g;
  const int tid = threadIdx.x;
  const int w = tid >> 6;
  const int l = tid & 63;
  const int m16 = l & 15;
  const int quad = l >> 4;

  __shared__ u16 Kl[2][BKV * 64];  // [buf][key][d]  linear, swizzled source
  __shared__ u16 Vl[2][64 * BKV];  // [buf][d][key]  linear, swizzled source
  __shared__ u16 Pl[4][16 * 64];   // per-wave [q][key], XOR-swizzled cols

  const float SC = 0.125f * LOG2E;
  const int qb = iq * BQ;
  const int ntiles = iq + 1;
  const int qglob = qb + w * 16 + m16;
  const int sw = (m16 & 7) << 3;  // u16-col XOR for reads of row (..16+m16)

  bf16x8 qf[2];
  {
    const u16* qrow = Qy + (bh * SEQ + qglob) * HEAD_DIM;
    qf[0] = __builtin_bit_cast(bf16x8, *(const u16x8*)&qrow[quad * 8]);
    qf[1] = __builtin_bit_cast(bf16x8, *(const u16x8*)&qrow[32 + quad * 8]);
  }

  floatx4 Oacc[4];  // O^T: col=q=m16, row=d = t*16 + quad*4 + r
#pragma unroll
  for (int t = 0; t < 4; ++t) Oacc[t] = (floatx4){0.f, 0.f, 0.f, 0.f};
  float mrow = -1e30f, lsum = 0.f;  // lsum: PER-LANE partial; reduced at end

  // prologue: stage tile 0 into buf 0
  stage_kv(K, Vt, bh, 0, tid, Kl[0], Vl[0]);
  __syncthreads();

  for (int it = 0; it < ntiles; ++it) {
    const int buf = it & 1;
    const int kt = it * BKV;
    if (it + 1 < ntiles)
      stage_kv(K, Vt, bh, kt + BKV, tid, Kl[buf ^ 1], Vl[buf ^ 1]);

    // ---- S^T = K Q^T (raw scores; scale folded into exp FMA) ----
    floatx4 s[4];
#pragma unroll
    for (int j = 0; j < 4; ++j) s[j] = (floatx4){0.f, 0.f, 0.f, 0.f};
    __builtin_amdgcn_s_setprio(1);
#pragma unroll
    for (int j = 0; j < 4; ++j)
#pragma unroll
      for (int kk = 0; kk < 2; ++kk) {
        const bf16x8 kf = __builtin_bit_cast(
            bf16x8, *(const u16x8*)&Kl[buf][(j * 16 + m16) * 64 +
                                            ((kk * 32 + quad * 8) ^ sw)]);
        s[j] = __builtin_amdgcn_mfma_f32_16x16x32_bf16(kf, qf[kk], s[j], 0, 0,
                                                       0);
      }
    __builtin_amdgcn_s_setprio(0);
    if (it == ntiles - 1) {
#pragma unroll
      for (int j = 0; j < 4; ++j) {
        const int key0 = kt + j * 16 + quad * 4;
#pragma unroll
        for (int r = 0; r < 4; ++r)
          if (key0 + r > qglob) s[j][r] = -1e30f;
      }
    }

    // ---- online softmax with defer-max (T13) ----
    float tm = s[0][0];
#pragma unroll
    for (int j = 0; j < 4; ++j)
#pragma unroll
      for (int r = 0; r < 4; ++r)
        if (j + r) tm = fmaxf(tm, s[j][r]);  // linear chain -> v_max3
    tm = fmaxf(tm, __shfl_xor(tm, 16, 64));
    tm = fmaxf(tm, __shfl_xor(tm, 32, 64));
    const float pm = tm * SC;
    if (!__all(pm <= mrow + 4.f)) {
      const float mn = fmaxf(mrow, pm);
      const float al = EXP2(mrow - mn);
      mrow = mn;
      lsum *= al;  // per-lane partial rescales identically (al row-uniform)
#pragma unroll
      for (int t = 0; t < 4; ++t)
#pragma unroll
        for (int r = 0; r < 4; ++r) Oacc[t][r] *= al;
    }

    float ls = 0.f;
#pragma unroll
    for (int j = 0; j < 4; ++j) {
      u16x4 pk;
#pragma unroll
      for (int r = 0; r < 4; ++r) {
        const float p = EXP2(__builtin_fmaf(s[j][r], SC, -mrow));
        ls += p;
        pk[r] = cvt_bf16(p);
      }
      *(u16x4*)&Pl[w][m16 * 64 + ((j * 16 + quad * 4) ^ sw)] = pk;
    }
    lsum += ls;  // cross-lane reduction deferred to epilogue

    // ---- O^T += V^T P^T (both from LDS, swizzled reads) ----
    bf16x8 pf[2];
    pf[0] = __builtin_bit_cast(
        bf16x8, *(const u16x8*)&Pl[w][m16 * 64 + ((quad * 8) ^ sw)]);
    pf[1] = __builtin_bit_cast(
        bf16x8, *(const u16x8*)&Pl[w][m16 * 64 + ((32 + quad * 8) ^ sw)]);
    __builtin_amdgcn_s_setprio(1);
#pragma unroll
    for (int t = 0; t < 4; ++t)
#pragma unroll
      for (int kk = 0; kk < 2; ++kk) {
        const bf16x8 vf = __builtin_bit_cast(
            bf16x8, *(const u16x8*)&Vl[buf][(t * 16 + m16) * 64 +
                                            ((kk * 32 + quad * 8) ^ sw)]);
        Oacc[t] = __builtin_amdgcn_mfma_f32_16x16x32_bf16(vf, pf[kk], Oacc[t],
                                                          0, 0, 0);
      }
    __builtin_amdgcn_s_setprio(0);
    __syncthreads();  // buf consumed; next iter may overwrite it
  }

  // ---- epilogue: reduce l across quads, then normalize + write O^T ----
  float lt = lsum;
  lt += __shfl_xor(lt, 16, 64);
  lt += __shfl_xor(lt, 32, 64);
  const float invl = 1.f / lt;
#pragma unroll
  for (int t = 0; t < 4; ++t) {
    u16x4 pk;
#pragma unroll
    for (int r = 0; r < 4; ++r) pk[r] = cvt_bf16(Oacc[t][r] * invl);
    *(u16x4*)&Qy[(bh * SEQ + qglob) * HEAD_DIM + t * 16 + quad * 4] = pk;
  }
}

// ======== launch ========
extern "C" void kernel_launch(void* const* d_in, const int* in_sizes, int n_in,
                              void* d_out, int out_size, void* d_ws,
                              size_t ws_size, hipStream_t stream) {
  const float* x = (const float*)d_in[0];
  const float* w_attn = (const float*)d_in[1];
  const float* b_attn = (const float*)d_in[2];
  const float* w_proj = (const float*)d_in[3];
  const float* b_proj = (const float*)d_in[4];
  float* out = (float*)d_out;

  // ws: q 8 | k 8 | vT 8 | wT_a 6 | wT_p 2 | xb 8  = 40 MB
  char* ws = (char*)d_ws;
  const size_t SZ = (size_t)BATCH * N_HEAD * SEQ * HEAD_DIM * sizeof(u16);
  u16* q = (u16*)(ws);
  u16* k = (u16*)(ws + SZ);
  u16* vT = (u16*)(ws + 2 * SZ);
  u16* wT_a = (u16*)(ws + 3 * SZ);
  u16* wT_p = (u16*)(ws + 3 * SZ + (size_t)3 * N_EMBD * N_EMBD * sizeof(u16));
  u16* xb = (u16*)(ws + 3 * SZ + (size_t)4 * N_EMBD * N_EMBD * sizeof(u16));

  prep<<<2048 + 4096, 256, 0, stream>>>(x, xb, w_attn, w_proj, wT_a, wT_p);

  gemm_qkv<<<dim3(3 * N_EMBD / 192, M_ROWS / 128), 512,
             (2 * 128 * 64 + 2 * 192 * 64) * sizeof(u16), stream>>>(
      xb, wT_a, b_attn, q, k, vT);

  flash_attn<<<NQT * 32, 256, 0, stream>>>(q, k, vT);

  gemm_proj<<<dim3(N_EMBD / 64, M_ROWS / 128), 256, 0, stream>>>(
      q, wT_p, b_proj, out);
}